// Round 8
// baseline (187.901 us; speedup 1.0000x reference)
//
#include <hip/hip_runtime.h>
#include <hip/hip_bf16.h>

// MDTA (multi-head cross attention with l2-normed q/k) for MI355X.
// B=8, N=4096, Ktok=256, C=512, H=8, D=64.
// Inputs f32, OUTPUT f32 (reference dtype; established r0-r7).
//
// Pipeline:
//  0) cvt:       Wq,Wk,Wv,Wo f32 -> bf16 in ws
//  1) gemm<0,1>: Q = l2norm_head(X @ Wq^T)        -> ws.Q   (32768x512 bf16)
//  2) gemm<0,1>: Kn = l2norm_head(S @ Wk^T)       -> ws.K   (2048x512)
//  3) gemm<1,1>: Vt[b][h][d][t] = (S @ Wv^T)^T    -> ws.Vt
//  4) attn:      O = softmax(temp * Q.K^T) @ V    -> ws.Q (in place)
//  5) gemm<2,0>: out = X + O @ Wo^T               -> d_out (f32!)

typedef __bf16 bf16;
typedef __attribute__((ext_vector_type(8))) __bf16 bf16x8;
typedef __attribute__((ext_vector_type(4))) float f32x4;

__device__ __forceinline__ void gload_lds16(const void* g, void* l) {
  __builtin_amdgcn_global_load_lds(
      (__attribute__((address_space(1))) void*)g,
      (__attribute__((address_space(3))) void*)l, 16, 0, 0);
}

__device__ __forceinline__ unsigned pack2(float a, float b) {
  unsigned short x = __builtin_bit_cast(unsigned short, (bf16)a);
  unsigned short y = __builtin_bit_cast(unsigned short, (bf16)b);
  return (unsigned)x | ((unsigned)y << 16);
}

// f32 -> bf16, 8 elems/thread
__global__ __launch_bounds__(256) void cvt_f32_bf16(
    const float* __restrict__ src, bf16* __restrict__ dst, int n8) {
  int i = blockIdx.x * 256 + threadIdx.x;
  if (i >= n8) return;
  float4 a = *(const float4*)(src + (size_t)i * 8);
  float4 b = *(const float4*)(src + (size_t)i * 8 + 4);
  uint4 v;
  v.x = pack2(a.x, a.y);
  v.y = pack2(a.z, a.w);
  v.z = pack2(b.x, b.y);
  v.w = pack2(b.z, b.w);
  *(uint4*)(dst + (size_t)i * 8) = v;
}

// ---------------------------------------------------------------------------
// C(MxN) = A(MxK) @ W(NxK)^T   with N=K=512 fixed. BM=BN=128, BK=32,
// 256 threads (4 waves, 2x2 wave grid, 64x64 per wave), mfma 16x16x32 bf16.
// AF32: A is f32, converted during LDS staging (reg-staged ds_write_b128).
// EPI 0: per-64-col (head) l2-normalize rows, store bf16
// EPI 1: transposed store into Vt[b][h][d][t]  (M must be 2048: b=m>>8,t=m&255)
// EPI 2: residual add from f32 Xres, store F32 to Cout
// ---------------------------------------------------------------------------
template <int EPI, bool AF32>
__global__ __launch_bounds__(256) void gemm_bt(
    const void* __restrict__ Ain, const bf16* __restrict__ W,
    void* __restrict__ Cout, const float* __restrict__ Xres) {
  __shared__ bf16 As[128 * 32];
  __shared__ bf16 Bs[128 * 32];

  const int tid = threadIdx.x;
  const int wid = tid >> 6, lane = tid & 63;
  const int wr = wid >> 1, wc = wid & 1;
  const int g = lane >> 4, c16 = lane & 15;
  const int tn = blockIdx.x & 3;   // N/128 = 4
  const int tm = blockIdx.x >> 2;
  const int m0 = tm * 128, n0 = tn * 128;

  f32x4 acc[4][4] = {};

  for (int kb = 0; kb < 512; kb += 32) {
#pragma unroll
    for (int i = 0; i < 2; ++i) {
      int c = i * 256 + tid;  // 16B-chunk id (8 bf16), 512 per tile
      int row = c >> 2, cc = c & 3;
      if (AF32) {
        const float* src =
            (const float*)Ain + (size_t)(m0 + row) * 512 + kb + cc * 8;
        float4 a = *(const float4*)src;
        float4 b = *(const float4*)(src + 4);
        uint4 v;
        v.x = pack2(a.x, a.y);
        v.y = pack2(a.z, a.w);
        v.z = pack2(b.x, b.y);
        v.w = pack2(b.z, b.w);
        *(uint4*)(As + c * 8) = v;
      } else {
        gload_lds16((const bf16*)Ain + (size_t)(m0 + row) * 512 + kb + cc * 8,
                    As + (i * 256 + (tid & ~63)) * 8);
      }
      gload_lds16(W + (size_t)(n0 + row) * 512 + kb + cc * 8,
                  Bs + (i * 256 + (tid & ~63)) * 8);
    }
    __syncthreads();

    bf16x8 af[4], bfr[4];
#pragma unroll
    for (int mi = 0; mi < 4; ++mi)
      af[mi] = *(const bf16x8*)(As + (wr * 64 + mi * 16 + c16) * 32 + g * 8);
#pragma unroll
    for (int ni = 0; ni < 4; ++ni)
      bfr[ni] = *(const bf16x8*)(Bs + (wc * 64 + ni * 16 + c16) * 32 + g * 8);
#pragma unroll
    for (int mi = 0; mi < 4; ++mi)
#pragma unroll
      for (int ni = 0; ni < 4; ++ni)
        acc[mi][ni] = __builtin_amdgcn_mfma_f32_16x16x32_bf16(
            af[mi], bfr[ni], acc[mi][ni], 0, 0, 0);
    __syncthreads();
  }

  // Epilogue. C/D frag: col = lane&15, row = (lane>>4)*4 + j   [m89]
  if (EPI == 0) {
    bf16* C = (bf16*)Cout;
    // l2 norm over the wave's 64 cols (= exactly one head).
#pragma unroll
    for (int mi = 0; mi < 4; ++mi) {
      float ss[4];
#pragma unroll
      for (int j = 0; j < 4; ++j) {
        float s = 0.f;
#pragma unroll
        for (int ni = 0; ni < 4; ++ni) {
          float v = acc[mi][ni][j];
          s += v * v;
        }
        ss[j] = s;
      }
#pragma unroll
      for (int msk = 1; msk < 16; msk <<= 1)
#pragma unroll
        for (int j = 0; j < 4; ++j) ss[j] += __shfl_xor(ss[j], msk, 64);
      float inv[4];
#pragma unroll
      for (int j = 0; j < 4; ++j) inv[j] = rsqrtf(fmaxf(ss[j], 1e-24f));
#pragma unroll
      for (int ni = 0; ni < 4; ++ni)
#pragma unroll
        for (int j = 0; j < 4; ++j) {
          size_t idx = (size_t)(m0 + wr * 64 + mi * 16 + g * 4 + j) * 512 +
                       n0 + wc * 64 + ni * 16 + c16;
          C[idx] = (bf16)(acc[mi][ni][j] * inv[j]);
        }
    }
  } else if (EPI == 1) {
    bf16* C = (bf16*)Cout;
    // transposed store: 4 j-values = 4 consecutive tokens at one (h,d) -> 8B
#pragma unroll
    for (int mi = 0; mi < 4; ++mi) {
      int m = m0 + wr * 64 + mi * 16 + g * 4;  // +j
      int b = m >> 8, t = m & 255;
#pragma unroll
      for (int ni = 0; ni < 4; ++ni) {
        int col = n0 + wc * 64 + ni * 16 + c16;
        int h = col >> 6, d = col & 63;
        uint2 v;
        v.x = pack2(acc[mi][ni][0], acc[mi][ni][1]);
        v.y = pack2(acc[mi][ni][2], acc[mi][ni][3]);
        *(uint2*)(C + ((size_t)((b * 8 + h) * 64 + d) * 256 + t)) = v;
      }
    }
  } else {
    float* C = (float*)Cout;  // f32 output with residual
#pragma unroll
    for (int mi = 0; mi < 4; ++mi)
#pragma unroll
      for (int ni = 0; ni < 4; ++ni)
#pragma unroll
        for (int j = 0; j < 4; ++j) {
          size_t idx = (size_t)(m0 + wr * 64 + mi * 16 + g * 4 + j) * 512 +
                       n0 + wc * 64 + ni * 16 + c16;
          C[idx] = acc[mi][ni][j] + Xres[idx];
        }
  }
}

// ---------------------------------------------------------------------------
// Fused attention. One block = (b, h, 128 q-rows), 512 threads = 8 waves,
// wave w owns q in [16w,16w+16). Full K=256 resident in LDS.
//   S^T = mfma(A=K tile, B=Q^T)  -> lane holds one q-col, 64 of 256 k-scores
//   softmax over k: lane-local + shfl_xor(16,32)
//   P -> LDS (bf16, swizzled), O = mfma(A=P, B=V^T)
// All LDS tiles XOR-swizzled: byte ^= ((row&7)<<4).
// ---------------------------------------------------------------------------
__global__ __launch_bounds__(512) void attn_fused(
    const bf16* __restrict__ Qn, const bf16* __restrict__ Kn,
    const bf16* __restrict__ Vt, const float* __restrict__ temp,
    bf16* __restrict__ O) {
  __shared__ __align__(16) char smem[147456];
  // [0,32768)        Ksm [256 t][64 d]
  // [32768,65536)    Vsm [64 d][256 t]
  // [65536,81920)    Qsm [128 q][64 d]
  // [81920,147456)   Psm [128 q][256 k]

  const int tid = threadIdx.x;
  const int w = tid >> 6, lane = tid & 63;
  const int g = lane >> 4, c16 = lane & 15;
  const int bx = blockIdx.x;
  const int nt = bx & 31, h = (bx >> 5) & 7, b = bx >> 8;
  const int n0 = nt * 128;

  // ---- stage K, V^T, Q (reg-staged so LDS writes can be swizzled)
  {
    const bf16* Ksrc = Kn + ((size_t)b * 256) * 512 + h * 64;
#pragma unroll
    for (int it = 0; it < 4; ++it) {
      int c = it * 512 + tid;  // 2048 chunks of 16B
      int t = c >> 3, dc = c & 7;
      int4 v = *(const int4*)(Ksrc + (size_t)t * 512 + dc * 8);
      int off = (t * 128 + dc * 16) ^ ((t & 7) << 4);
      *(int4*)(smem + off) = v;
    }
    const bf16* Vsrc = Vt + (size_t)((b * 8 + h) * 64) * 256;
#pragma unroll
    for (int it = 0; it < 4; ++it) {
      int c = it * 512 + tid;
      int d = c >> 5, tc = c & 31;
      int4 v = *(const int4*)(Vsrc + (size_t)d * 256 + tc * 8);
      int off = (d * 512 + tc * 16) ^ ((d & 7) << 4);
      *(int4*)(smem + 32768 + off) = v;
    }
    const bf16* Qsrc = Qn + ((size_t)b * 4096 + n0) * 512 + h * 64;
#pragma unroll
    for (int it = 0; it < 2; ++it) {
      int c = it * 512 + tid;  // 1024 chunks
      int q = c >> 3, dc = c & 7;
      int4 v = *(const int4*)(Qsrc + (size_t)q * 512 + dc * 8);
      int off = (q * 128 + dc * 16) ^ ((q & 7) << 4);
      *(int4*)(smem + 65536 + off) = v;
    }
  }
  __syncthreads();

  const int q = w * 16 + c16;  // this lane's q (col of S^T, row of P/O)

  // ---- S^T
  f32x4 sacc[16] = {};
  bf16x8 qf[2];
#pragma unroll
  for (int s = 0; s < 2; ++s) {
    int off = (q * 128 + s * 64 + g * 16) ^ ((q & 7) << 4);
    qf[s] = *(const bf16x8*)(smem + 65536 + off);
  }
#pragma unroll
  for (int mi = 0; mi < 16; ++mi) {
#pragma unroll
    for (int s = 0; s < 2; ++s) {
      int t = mi * 16 + c16;
      int off = (t * 128 + s * 64 + g * 16) ^ ((t & 7) << 4);
      bf16x8 kf = *(const bf16x8*)(smem + off);
      sacc[mi] = __builtin_amdgcn_mfma_f32_16x16x32_bf16(kf, qf[s], sacc[mi],
                                                         0, 0, 0);
    }
  }

  // ---- softmax over k (lane holds k = mi*16 + g*4 + j; partners lane^16,^32)
  float tv = temp[h];
  float mx = -1e30f;
#pragma unroll
  for (int mi = 0; mi < 16; ++mi)
#pragma unroll
    for (int j = 0; j < 4; ++j) {
      sacc[mi][j] *= tv;
      mx = fmaxf(mx, sacc[mi][j]);
    }
  mx = fmaxf(mx, __shfl_xor(mx, 16, 64));
  mx = fmaxf(mx, __shfl_xor(mx, 32, 64));
  float sum = 0.f;
#pragma unroll
  for (int mi = 0; mi < 16; ++mi)
#pragma unroll
    for (int j = 0; j < 4; ++j) {
      float p = __expf(sacc[mi][j] - mx);
      sacc[mi][j] = p;
      sum += p;
    }
  sum += __shfl_xor(sum, 16, 64);
  sum += __shfl_xor(sum, 32, 64);
  float inv = 1.0f / sum;

  // ---- P[q][k] -> LDS (bf16, swizzled)
#pragma unroll
  for (int mi = 0; mi < 16; ++mi) {
    uint2 v;
    v.x = pack2(sacc[mi][0] * inv, sacc[mi][1] * inv);
    v.y = pack2(sacc[mi][2] * inv, sacc[mi][3] * inv);
    int off = (q * 512 + mi * 32 + g * 8) ^ ((q & 7) << 4);
    *(uint2*)(smem + 81920 + off) = v;
  }
  __syncthreads();

  // ---- O = P @ V
  f32x4 oacc[4] = {};
#pragma unroll
  for (int ks = 0; ks < 8; ++ks) {
    int offa = (q * 512 + ks * 64 + g * 16) ^ ((q & 7) << 4);
    bf16x8 pa = *(const bf16x8*)(smem + 81920 + offa);
#pragma unroll
    for (int ni = 0; ni < 4; ++ni) {
      int d = ni * 16 + c16;
      int offb = (d * 512 + ks * 64 + g * 16) ^ ((d & 7) << 4);
      bf16x8 vb = *(const bf16x8*)(smem + 32768 + offb);
      oacc[ni] = __builtin_amdgcn_mfma_f32_16x16x32_bf16(pa, vb, oacc[ni],
                                                         0, 0, 0);
    }
  }

  // ---- store O (overwrites Q workspace in place; disjoint per (h,nt))
  bf16* Orow = O + ((size_t)b * 4096 + n0 + w * 16) * 512 + h * 64;
#pragma unroll
  for (int ni = 0; ni < 4; ++ni)
#pragma unroll
    for (int j = 0; j < 4; ++j)
      Orow[(size_t)(g * 4 + j) * 512 + ni * 16 + c16] = (bf16)oacc[ni][j];
}

// ---------------------------------------------------------------------------
extern "C" void kernel_launch(void* const* d_in, const int* in_sizes, int n_in,
                              void* d_out, int out_size, void* d_ws,
                              size_t ws_size, hipStream_t stream) {
  const float* X = (const float*)d_in[0];
  const float* S = (const float*)d_in[1];
  const float* Wq = (const float*)d_in[2];
  const float* Wk = (const float*)d_in[3];
  const float* Wv = (const float*)d_in[4];
  const float* Wo = (const float*)d_in[5];
  const float* temp = (const float*)d_in[6];
  float* out = (float*)d_out;  // f32 output (reference dtype)

  char* ws = (char*)d_ws;
  bf16* Qws = (bf16*)ws;                      // 32768*512*2 = 33,554,432 B
  bf16* Kws = (bf16*)(ws + 33554432);         //  2048*512*2 =  2,097,152 B
  bf16* Vtws = (bf16*)(ws + 35651584);        //  8*8*64*256*2 = 2,097,152 B
  bf16* Wqb = (bf16*)(ws + 37748736);         //  512*512*2 = 524,288 B each
  bf16* Wkb = (bf16*)(ws + 38273024);
  bf16* Wvb = (bf16*)(ws + 38797312);
  bf16* Wob = (bf16*)(ws + 39321600);

  cvt_f32_bf16<<<dim3(128), dim3(256), 0, stream>>>(Wq, Wqb, 32768);
  cvt_f32_bf16<<<dim3(128), dim3(256), 0, stream>>>(Wk, Wkb, 32768);
  cvt_f32_bf16<<<dim3(128), dim3(256), 0, stream>>>(Wv, Wvb, 32768);
  cvt_f32_bf16<<<dim3(128), dim3(256), 0, stream>>>(Wo, Wob, 32768);

  gemm_bt<0, true><<<dim3(1024), dim3(256), 0, stream>>>(X, Wqb, Qws, nullptr);
  gemm_bt<0, true><<<dim3(64), dim3(256), 0, stream>>>(S, Wkb, Kws, nullptr);
  gemm_bt<1, true><<<dim3(64), dim3(256), 0, stream>>>(S, Wvb, Vtws, nullptr);
  attn_fused<<<dim3(2048), dim3(512), 0, stream>>>(Qws, Kws, Vtws, temp, Qws);
  gemm_bt<2, false><<<dim3(1024), dim3(256), 0, stream>>>(Qws, Wob, out, X);
}

// Round 9
// 153.132 us; speedup vs baseline: 1.2270x; 1.2270x over previous
//
#include <hip/hip_runtime.h>
#include <hip/hip_bf16.h>

// MDTA (multi-head cross attention with l2-normed q/k) for MI355X.
// B=8, N=4096, Ktok=256, C=512, H=8, D=64. Inputs f32, output f32.
//
// R8: 187.9us baseline (serial 2-barrier GEMMs, 9 launches).
// R9: 2-phase double-buffered GEMM pipeline (stage t+1 before compute t,
//     one barrier/iter), Q/K/V projections fused into one launch, XCD-aware
//     bijective swizzle so same-A-panel tiles share an XCD L2, cvt fused.
//
// Pipeline (4 launches):
//  1) cvt_all:  Wq,Wk,Wv,Wo f32 -> bf16 in ws
//  2) proj_all: Q  = l2norm_head(X @ Wq^T) -> ws.Q  (blocks 0..1023)
//               Kn = l2norm_head(S @ Wk^T) -> ws.K  (blocks 1024..1087)
//               Vt = (S @ Wv^T)^T          -> ws.Vt (blocks 1088..1151)
//  3) attn:     O = softmax(temp * Q.K^T) @ V -> ws.Q (in place)
//  4) out_gemm: out = X + O @ Wo^T -> d_out (f32)

typedef __bf16 bf16;
typedef __attribute__((ext_vector_type(8))) __bf16 bf16x8;
typedef __attribute__((ext_vector_type(4))) float f32x4;

__device__ __forceinline__ void gload_lds16(const void* g, void* l) {
  __builtin_amdgcn_global_load_lds(
      (__attribute__((address_space(1))) void*)g,
      (__attribute__((address_space(3))) void*)l, 16, 0, 0);
}

__device__ __forceinline__ unsigned pack2(float a, float b) {
  unsigned short x = __builtin_bit_cast(unsigned short, (bf16)a);
  unsigned short y = __builtin_bit_cast(unsigned short, (bf16)b);
  return (unsigned)x | ((unsigned)y << 16);
}

// ---------------------------------------------------------------------------
// All four weights f32 -> bf16 in one launch. 512 blocks x 256 thr x 8 elems.
// ---------------------------------------------------------------------------
__global__ __launch_bounds__(256) void cvt_all(
    const float* __restrict__ Wq, const float* __restrict__ Wk,
    const float* __restrict__ Wv, const float* __restrict__ Wo,
    bf16* __restrict__ Wqb, bf16* __restrict__ Wkb, bf16* __restrict__ Wvb,
    bf16* __restrict__ Wob) {
  int i = blockIdx.x * 256 + threadIdx.x;  // chunk id, 32768 per weight
  int w = i >> 15, r = i & 32767;
  const float* src = (w == 0) ? Wq : (w == 1) ? Wk : (w == 2) ? Wv : Wo;
  bf16* dst = (w == 0) ? Wqb : (w == 1) ? Wkb : (w == 2) ? Wvb : Wob;
  float4 a = *(const float4*)(src + (size_t)r * 8);
  float4 b = *(const float4*)(src + (size_t)r * 8 + 4);
  uint4 v;
  v.x = pack2(a.x, a.y);
  v.y = pack2(a.z, a.w);
  v.z = pack2(b.x, b.y);
  v.w = pack2(b.z, b.w);
  *(uint4*)(dst + (size_t)r * 8) = v;
}

// ---------------------------------------------------------------------------
// Fused Q/K/V projection. C(128x128 tile) = A(f32, Mx512) @ W(bf16,512x512)^T.
// BK=32, 16 K-steps, 2-phase double-buffered: stage(t+1) issued BEFORE
// compute(t), single barrier per iter. A: f32 global->reg->cvt->ds_write
// (issue-early / write-late). B: global_load_lds into the back buffer.
// Epilogue by logical block id: EPI0 l2norm (Q, Kn), EPI1 transposed Vt.
// ---------------------------------------------------------------------------
__global__ __launch_bounds__(256) void proj_all(
    const float* __restrict__ X, const float* __restrict__ S,
    const bf16* __restrict__ Wqb, const bf16* __restrict__ Wkb,
    const bf16* __restrict__ Wvb, bf16* __restrict__ Q,
    bf16* __restrict__ Kn, bf16* __restrict__ Vt) {
  __shared__ __align__(16) bf16 As[2][128 * 32];
  __shared__ __align__(16) bf16 Bs[2][128 * 32];

  // XCD swizzle: 1152 blocks = 8 XCDs x 144. Same-A-panel (same tm) tiles
  // get consecutive logical ids -> same XCD L2.
  const int lg = (blockIdx.x & 7) * 144 + (blockIdx.x >> 3);

  const float* A;
  const bf16* W;
  int m0;
  int kind;  // 0=Q, 1=K, 2=V
  if (lg < 1024) {
    kind = 0;
    A = X;
    W = Wqb;
    m0 = (lg >> 2) * 128;
  } else if (lg < 1088) {
    kind = 1;
    A = S;
    W = Wkb;
    m0 = ((lg - 1024) >> 2) * 128;
  } else {
    kind = 2;
    A = S;
    W = Wvb;
    m0 = ((lg - 1088) >> 2) * 128;
  }
  const int n0 = (lg & 3) * 128;

  const int tid = threadIdx.x;
  const int wid = tid >> 6, lane = tid & 63;
  const int wr = wid >> 1, wc = wid & 1;
  const int g = lane >> 4, c16 = lane & 15;

  // Per-thread staging coords: chunk c = i*256 + tid (i=0,1), row/col in tile.
  const int c0 = tid, c1 = 256 + tid;
  const int r0 = c0 >> 2, cc0 = c0 & 3;
  const int r1 = c1 >> 2, cc1 = c1 & 3;

  f32x4 acc[4][4] = {};

  // ---- prologue: stage tile 0 into buffer 0
  {
    const float* s0 = A + (size_t)(m0 + r0) * 512 + cc0 * 8;
    const float* s1 = A + (size_t)(m0 + r1) * 512 + cc1 * 8;
    float4 a0 = *(const float4*)s0, b0 = *(const float4*)(s0 + 4);
    float4 a1 = *(const float4*)s1, b1 = *(const float4*)(s1 + 4);
    uint4 v0, v1;
    v0.x = pack2(a0.x, a0.y); v0.y = pack2(a0.z, a0.w);
    v0.z = pack2(b0.x, b0.y); v0.w = pack2(b0.z, b0.w);
    v1.x = pack2(a1.x, a1.y); v1.y = pack2(a1.z, a1.w);
    v1.z = pack2(b1.x, b1.y); v1.w = pack2(b1.z, b1.w);
    *(uint4*)(As[0] + c0 * 8) = v0;
    *(uint4*)(As[0] + c1 * 8) = v1;
    gload_lds16(W + (size_t)(n0 + r0) * 512 + cc0 * 8,
                Bs[0] + (tid & ~63) * 8);
    gload_lds16(W + (size_t)(n0 + r1) * 512 + cc1 * 8,
                Bs[0] + (256 + (tid & ~63)) * 8);
  }
  __syncthreads();

  int cur = 0;
  for (int t = 0; t < 16; ++t) {
    const int kb = (t + 1) * 32;
    float4 a0, b0, a1, b1;
    if (t < 15) {
      // issue A loads (t+1) early; issue B global_load_lds into back buffer
      const float* s0 = A + (size_t)(m0 + r0) * 512 + kb + cc0 * 8;
      const float* s1 = A + (size_t)(m0 + r1) * 512 + kb + cc1 * 8;
      a0 = *(const float4*)s0;
      b0 = *(const float4*)(s0 + 4);
      a1 = *(const float4*)s1;
      b1 = *(const float4*)(s1 + 4);
      gload_lds16(W + (size_t)(n0 + r0) * 512 + kb + cc0 * 8,
                  Bs[cur ^ 1] + (tid & ~63) * 8);
      gload_lds16(W + (size_t)(n0 + r1) * 512 + kb + cc1 * 8,
                  Bs[cur ^ 1] + (256 + (tid & ~63)) * 8);
    }

    // compute tile t
    bf16x8 af[4], bfr[4];
#pragma unroll
    for (int mi = 0; mi < 4; ++mi)
      af[mi] =
          *(const bf16x8*)(As[cur] + (wr * 64 + mi * 16 + c16) * 32 + g * 8);
#pragma unroll
    for (int ni = 0; ni < 4; ++ni)
      bfr[ni] =
          *(const bf16x8*)(Bs[cur] + (wc * 64 + ni * 16 + c16) * 32 + g * 8);
#pragma unroll
    for (int mi = 0; mi < 4; ++mi)
#pragma unroll
      for (int ni = 0; ni < 4; ++ni)
        acc[mi][ni] = __builtin_amdgcn_mfma_f32_16x16x32_bf16(
            af[mi], bfr[ni], acc[mi][ni], 0, 0, 0);

    if (t < 15) {
      // write-late: convert staged A regs into back buffer
      uint4 v0, v1;
      v0.x = pack2(a0.x, a0.y); v0.y = pack2(a0.z, a0.w);
      v0.z = pack2(b0.x, b0.y); v0.w = pack2(b0.z, b0.w);
      v1.x = pack2(a1.x, a1.y); v1.y = pack2(a1.z, a1.w);
      v1.z = pack2(b1.x, b1.y); v1.w = pack2(b1.z, b1.w);
      *(uint4*)(As[cur ^ 1] + c0 * 8) = v0;
      *(uint4*)(As[cur ^ 1] + c1 * 8) = v1;
    }
    __syncthreads();
    cur ^= 1;
  }

  // ---- epilogue. C/D frag: col = lane&15, row = (lane>>4)*4 + j   [m89]
  if (kind != 2) {
    bf16* C = (kind == 0) ? Q : Kn;
    // l2 norm over the wave's 64 cols (= exactly one head).
#pragma unroll
    for (int mi = 0; mi < 4; ++mi) {
      float ss[4];
#pragma unroll
      for (int j = 0; j < 4; ++j) {
        float s = 0.f;
#pragma unroll
        for (int ni = 0; ni < 4; ++ni) {
          float v = acc[mi][ni][j];
          s += v * v;
        }
        ss[j] = s;
      }
#pragma unroll
      for (int msk = 1; msk < 16; msk <<= 1)
#pragma unroll
        for (int j = 0; j < 4; ++j) ss[j] += __shfl_xor(ss[j], msk, 64);
      float inv[4];
#pragma unroll
      for (int j = 0; j < 4; ++j) inv[j] = rsqrtf(fmaxf(ss[j], 1e-24f));
#pragma unroll
      for (int ni = 0; ni < 4; ++ni)
#pragma unroll
        for (int j = 0; j < 4; ++j) {
          size_t idx = (size_t)(m0 + wr * 64 + mi * 16 + g * 4 + j) * 512 +
                       n0 + wc * 64 + ni * 16 + c16;
          C[idx] = (bf16)(acc[mi][ni][j] * inv[j]);
        }
    }
  } else {
    // transposed store into Vt[b][h][d][t]: 4 j = 4 consecutive tokens -> 8B
#pragma unroll
    for (int mi = 0; mi < 4; ++mi) {
      int m = m0 + wr * 64 + mi * 16 + g * 4;  // +j
      int b = m >> 8, tt = m & 255;
#pragma unroll
      for (int ni = 0; ni < 4; ++ni) {
        int col = n0 + wc * 64 + ni * 16 + c16;
        int h = col >> 6, d = col & 63;
        uint2 v;
        v.x = pack2(acc[mi][ni][0], acc[mi][ni][1]);
        v.y = pack2(acc[mi][ni][2], acc[mi][ni][3]);
        *(uint2*)(Vt + ((size_t)((b * 8 + h) * 64 + d) * 256 + tt)) = v;
      }
    }
  }
}

// ---------------------------------------------------------------------------
// out = X + O @ Wo^T, f32 output. Same 2-phase pipeline; both operands bf16
// via global_load_lds (4 per iter into the back buffer).
// ---------------------------------------------------------------------------
__global__ __launch_bounds__(256) void out_gemm(
    const bf16* __restrict__ O, const bf16* __restrict__ Wob,
    const float* __restrict__ Xres, float* __restrict__ out) {
  __shared__ __align__(16) bf16 As[2][128 * 32];
  __shared__ __align__(16) bf16 Bs[2][128 * 32];

  const int lg = (blockIdx.x & 7) * 128 + (blockIdx.x >> 3);  // XCD swizzle
  const int m0 = (lg >> 2) * 128, n0 = (lg & 3) * 128;

  const int tid = threadIdx.x;
  const int wid = tid >> 6, lane = tid & 63;
  const int wr = wid >> 1, wc = wid & 1;
  const int g = lane >> 4, c16 = lane & 15;
  const int c0 = tid, c1 = 256 + tid;
  const int r0 = c0 >> 2, cc0 = c0 & 3;
  const int r1 = c1 >> 2, cc1 = c1 & 3;

  f32x4 acc[4][4] = {};

  gload_lds16(O + (size_t)(m0 + r0) * 512 + cc0 * 8, As[0] + (tid & ~63) * 8);
  gload_lds16(O + (size_t)(m0 + r1) * 512 + cc1 * 8,
              As[0] + (256 + (tid & ~63)) * 8);
  gload_lds16(Wob + (size_t)(n0 + r0) * 512 + cc0 * 8,
              Bs[0] + (tid & ~63) * 8);
  gload_lds16(Wob + (size_t)(n0 + r1) * 512 + cc1 * 8,
              Bs[0] + (256 + (tid & ~63)) * 8);
  __syncthreads();

  int cur = 0;
  for (int t = 0; t < 16; ++t) {
    const int kb = (t + 1) * 32;
    if (t < 15) {
      gload_lds16(O + (size_t)(m0 + r0) * 512 + kb + cc0 * 8,
                  As[cur ^ 1] + (tid & ~63) * 8);
      gload_lds16(O + (size_t)(m0 + r1) * 512 + kb + cc1 * 8,
                  As[cur ^ 1] + (256 + (tid & ~63)) * 8);
      gload_lds16(Wob + (size_t)(n0 + r0) * 512 + kb + cc0 * 8,
                  Bs[cur ^ 1] + (tid & ~63) * 8);
      gload_lds16(Wob + (size_t)(n0 + r1) * 512 + kb + cc1 * 8,
                  Bs[cur ^ 1] + (256 + (tid & ~63)) * 8);
    }
    bf16x8 af[4], bfr[4];
#pragma unroll
    for (int mi = 0; mi < 4; ++mi)
      af[mi] =
          *(const bf16x8*)(As[cur] + (wr * 64 + mi * 16 + c16) * 32 + g * 8);
#pragma unroll
    for (int ni = 0; ni < 4; ++ni)
      bfr[ni] =
          *(const bf16x8*)(Bs[cur] + (wc * 64 + ni * 16 + c16) * 32 + g * 8);
#pragma unroll
    for (int mi = 0; mi < 4; ++mi)
#pragma unroll
      for (int ni = 0; ni < 4; ++ni)
        acc[mi][ni] = __builtin_amdgcn_mfma_f32_16x16x32_bf16(
            af[mi], bfr[ni], acc[mi][ni], 0, 0, 0);
    __syncthreads();
    cur ^= 1;
  }

#pragma unroll
  for (int mi = 0; mi < 4; ++mi)
#pragma unroll
    for (int ni = 0; ni < 4; ++ni)
#pragma unroll
      for (int j = 0; j < 4; ++j) {
        size_t idx = (size_t)(m0 + wr * 64 + mi * 16 + g * 4 + j) * 512 + n0 +
                     wc * 64 + ni * 16 + c16;
        out[idx] = acc[mi][ni][j] + Xres[idx];
      }
}

// ---------------------------------------------------------------------------
// Fused attention (unchanged from R8-pass). Block = (b,h,128 q), 512 thr.
// S^T = mfma(K, Q^T); softmax lane-local + shfl(16,32); P via swizzled LDS;
// O = mfma(P, V^T). All LDS tiles XOR-swizzled byte^=((row&7)<<4).
// ---------------------------------------------------------------------------
__global__ __launch_bounds__(512) void attn_fused(
    const bf16* __restrict__ Qn, const bf16* __restrict__ Kn,
    const bf16* __restrict__ Vt, const float* __restrict__ temp,
    bf16* __restrict__ O) {
  __shared__ __align__(16) char smem[147456];
  // [0,32768) Ksm [256t][64d] | [32768,65536) Vsm [64d][256t]
  // [65536,81920) Qsm [128q][64d] | [81920,147456) Psm [128q][256k]

  const int tid = threadIdx.x;
  const int w = tid >> 6, lane = tid & 63;
  const int g = lane >> 4, c16 = lane & 15;
  const int bx = blockIdx.x;
  const int nt = bx & 31, h = (bx >> 5) & 7, b = bx >> 8;
  const int n0 = nt * 128;

  {
    const bf16* Ksrc = Kn + ((size_t)b * 256) * 512 + h * 64;
#pragma unroll
    for (int it = 0; it < 4; ++it) {
      int c = it * 512 + tid;
      int t = c >> 3, dc = c & 7;
      int4 v = *(const int4*)(Ksrc + (size_t)t * 512 + dc * 8);
      int off = (t * 128 + dc * 16) ^ ((t & 7) << 4);
      *(int4*)(smem + off) = v;
    }
    const bf16* Vsrc = Vt + (size_t)((b * 8 + h) * 64) * 256;
#pragma unroll
    for (int it = 0; it < 4; ++it) {
      int c = it * 512 + tid;
      int d = c >> 5, tc = c & 31;
      int4 v = *(const int4*)(Vsrc + (size_t)d * 256 + tc * 8);
      int off = (d * 512 + tc * 16) ^ ((d & 7) << 4);
      *(int4*)(smem + 32768 + off) = v;
    }
    const bf16* Qsrc = Qn + ((size_t)b * 4096 + n0) * 512 + h * 64;
#pragma unroll
    for (int it = 0; it < 2; ++it) {
      int c = it * 512 + tid;
      int q = c >> 3, dc = c & 7;
      int4 v = *(const int4*)(Qsrc + (size_t)q * 512 + dc * 8);
      int off = (q * 128 + dc * 16) ^ ((q & 7) << 4);
      *(int4*)(smem + 65536 + off) = v;
    }
  }
  __syncthreads();

  const int q = w * 16 + c16;

  f32x4 sacc[16] = {};
  bf16x8 qf[2];
#pragma unroll
  for (int s = 0; s < 2; ++s) {
    int off = (q * 128 + s * 64 + g * 16) ^ ((q & 7) << 4);
    qf[s] = *(const bf16x8*)(smem + 65536 + off);
  }
#pragma unroll
  for (int mi = 0; mi < 16; ++mi) {
#pragma unroll
    for (int s = 0; s < 2; ++s) {
      int t = mi * 16 + c16;
      int off = (t * 128 + s * 64 + g * 16) ^ ((t & 7) << 4);
      bf16x8 kf = *(const bf16x8*)(smem + off);
      sacc[mi] = __builtin_amdgcn_mfma_f32_16x16x32_bf16(kf, qf[s], sacc[mi],
                                                         0, 0, 0);
    }
  }

  float tv = temp[h];
  float mx = -1e30f;
#pragma unroll
  for (int mi = 0; mi < 16; ++mi)
#pragma unroll
    for (int j = 0; j < 4; ++j) {
      sacc[mi][j] *= tv;
      mx = fmaxf(mx, sacc[mi][j]);
    }
  mx = fmaxf(mx, __shfl_xor(mx, 16, 64));
  mx = fmaxf(mx, __shfl_xor(mx, 32, 64));
  float sum = 0.f;
#pragma unroll
  for (int mi = 0; mi < 16; ++mi)
#pragma unroll
    for (int j = 0; j < 4; ++j) {
      float p = __expf(sacc[mi][j] - mx);
      sacc[mi][j] = p;
      sum += p;
    }
  sum += __shfl_xor(sum, 16, 64);
  sum += __shfl_xor(sum, 32, 64);
  float inv = 1.0f / sum;

#pragma unroll
  for (int mi = 0; mi < 16; ++mi) {
    uint2 v;
    v.x = pack2(sacc[mi][0] * inv, sacc[mi][1] * inv);
    v.y = pack2(sacc[mi][2] * inv, sacc[mi][3] * inv);
    int off = (q * 512 + mi * 32 + g * 8) ^ ((q & 7) << 4);
    *(uint2*)(smem + 81920 + off) = v;
  }
  __syncthreads();

  f32x4 oacc[4] = {};
#pragma unroll
  for (int ks = 0; ks < 8; ++ks) {
    int offa = (q * 512 + ks * 64 + g * 16) ^ ((q & 7) << 4);
    bf16x8 pa = *(const bf16x8*)(smem + 81920 + offa);
#pragma unroll
    for (int ni = 0; ni < 4; ++ni) {
      int d = ni * 16 + c16;
      int offb = (d * 512 + ks * 64 + g * 16) ^ ((d & 7) << 4);
      bf16x8 vb = *(const bf16x8*)(smem + 32768 + offb);
      oacc[ni] = __builtin_amdgcn_mfma_f32_16x16x32_bf16(pa, vb, oacc[ni],
                                                         0, 0, 0);
    }
  }

  bf16* Orow = O + ((size_t)b * 4096 + n0 + w * 16) * 512 + h * 64;
#pragma unroll
  for (int ni = 0; ni < 4; ++ni)
#pragma unroll
    for (int j = 0; j < 4; ++j)
      Orow[(size_t)(g * 4 + j) * 512 + ni * 16 + c16] = (bf16)oacc[ni][j];
}

// ---------------------------------------------------------------------------
extern "C" void kernel_launch(void* const* d_in, const int* in_sizes, int n_in,
                              void* d_out, int out_size, void* d_ws,
                              size_t ws_size, hipStream_t stream) {
  const float* X = (const float*)d_in[0];
  const float* S = (const float*)d_in[1];
  const float* Wq = (const float*)d_in[2];
  const float* Wk = (const float*)d_in[3];
  const float* Wv = (const float*)d_in[4];
  const float* Wo = (const float*)d_in[5];
  const float* temp = (const float*)d_in[6];
  float* out = (float*)d_out;

  char* ws = (char*)d_ws;
  bf16* Qws = (bf16*)ws;                      // 32768*512*2 = 33,554,432 B
  bf16* Kws = (bf16*)(ws + 33554432);         //  2048*512*2 =  2,097,152 B
  bf16* Vtws = (bf16*)(ws + 35651584);        //  8*8*64*256*2 = 2,097,152 B
  bf16* Wqb = (bf16*)(ws + 37748736);         //  512*512*2 = 524,288 B each
  bf16* Wkb = (bf16*)(ws + 38273024);
  bf16* Wvb = (bf16*)(ws + 38797312);
  bf16* Wob = (bf16*)(ws + 39321600);

  cvt_all<<<dim3(512), dim3(256), 0, stream>>>(Wq, Wk, Wv, Wo, Wqb, Wkb, Wvb,
                                               Wob);
  proj_all<<<dim3(1152), dim3(256), 0, stream>>>(X, S, Wqb, Wkb, Wvb, Qws,
                                                 Kws, Vtws);
  attn_fused<<<dim3(2048), dim3(512), 0, stream>>>(Qws, Kws, Vtws, temp, Qws);
  out_gemm<<<dim3(1024), dim3(256), 0, stream>>>(Qws, Wob, X, out);
}